// Round 1
// baseline (31556.897 us; speedup 1.0000x reference)
//
#include <hip/hip_runtime.h>

#define WN 32          // WIDTH
#define HID 8          // WIDTH/4
#define DEPTH 4

__global__ void zero_kernel(float* __restrict__ agg, int* __restrict__ cnt, int n, int nagg) {
    int i = blockIdx.x * blockDim.x + threadIdx.x;
    if (i < nagg) agg[i] = 0.0f;
    if (i < n) cnt[i] = 0;
}

__global__ void h0_kernel(const float* __restrict__ x, const float* __restrict__ fc1_w,
                          const float* __restrict__ fc1_b, float* __restrict__ h, int n) {
    __shared__ float s_w[WN * 3];
    __shared__ float s_b[WN];
    int t = threadIdx.x;
    if (t < WN * 3) s_w[t] = fc1_w[t];
    if (t < WN) s_b[t] = fc1_b[t];
    __syncthreads();
    int i = blockIdx.x * blockDim.x + t;
    if (i >= n) return;
    float x0 = x[3 * i], x1 = x[3 * i + 1], x2 = x[3 * i + 2];
#pragma unroll
    for (int j = 0; j < WN; j++) {
        h[i * WN + j] = s_b[j] + s_w[j * 3] * x0 + s_w[j * 3 + 1] * x1 + s_w[j * 3 + 2] * x2;
    }
}

__global__ void count_kernel(const int* __restrict__ eidx, int* __restrict__ cnt, int e_cnt) {
    int e = blockIdx.x * blockDim.x + threadIdx.x;
    if (e >= e_cnt) return;
    int dst = eidx[e_cnt + e];
    atomicAdd(&cnt[dst], 1);
}

__global__ void inv_kernel(const int* __restrict__ cnt, float* __restrict__ inv, int n) {
    int i = blockIdx.x * blockDim.x + threadIdx.x;
    if (i >= n) return;
    int c = cnt[i];
    inv[i] = 1.0f / (float)(c > 1 ? c : 1);
}

// One thread per edge: recompute per-edge weight vector w (3->8 relu ->32 MLP),
// gather h[src] (128B contiguous), scatter-atomic msg into agg[dst].
__global__ void edge_kernel(const int* __restrict__ eidx, const float* __restrict__ ea,
                            const float* __restrict__ h, float* __restrict__ agg,
                            const float* __restrict__ kw1, const float* __restrict__ kb1,
                            const float* __restrict__ kw2, const float* __restrict__ kb2,
                            int e_cnt) {
    __shared__ float s_kw1[HID * 3];
    __shared__ float s_kb1[HID];
    __shared__ float s_kw2[WN * HID];
    __shared__ float s_kb2[WN];
    int t = threadIdx.x;
    if (t < HID * 3) s_kw1[t] = kw1[t];
    if (t < HID) s_kb1[t] = kb1[t];
    if (t < WN * HID) s_kw2[t] = kw2[t];
    if (t < WN) s_kb2[t] = kb2[t];
    __syncthreads();
    int e = blockIdx.x * blockDim.x + t;
    if (e >= e_cnt) return;
    int src = eidx[e];
    int dst = eidx[e_cnt + e];
    float a0 = ea[3 * e], a1 = ea[3 * e + 1], a2 = ea[3 * e + 2];
    float hid[HID];
#pragma unroll
    for (int j = 0; j < HID; j++) {
        float v = s_kb1[j] + s_kw1[j * 3] * a0 + s_kw1[j * 3 + 1] * a1 + s_kw1[j * 3 + 2] * a2;
        hid[j] = v > 0.0f ? v : 0.0f;
    }
    const float* hs = h + (size_t)src * WN;
    float* ag = agg + (size_t)dst * WN;
#pragma unroll
    for (int o = 0; o < WN; o++) {
        float w = s_kb2[o];
#pragma unroll
        for (int j = 0; j < HID; j++) w += s_kw2[o * HID + j] * hid[j];
        atomicAdd(&ag[o], hs[o] * w);
    }
}

// Per node: h = relu(agg*inv + h@root + cbias); also resets agg to 0 for next layer.
__global__ void update_kernel(float* __restrict__ h, float* __restrict__ agg,
                              const float* __restrict__ inv,
                              const float* __restrict__ root, const float* __restrict__ cbias,
                              int n) {
    __shared__ float s_root[WN * WN];
    __shared__ float s_cb[WN];
    int t = threadIdx.x;
    for (int i = t; i < WN * WN; i += blockDim.x) s_root[i] = root[i];
    if (t < WN) s_cb[t] = cbias[t];
    __syncthreads();
    int i = blockIdx.x * blockDim.x + t;
    if (i >= n) return;
    float hv[WN];
#pragma unroll
    for (int k = 0; k < WN; k++) hv[k] = h[(size_t)i * WN + k];
    float ic = inv[i];
#pragma unroll
    for (int o = 0; o < WN; o++) {
        float acc = agg[(size_t)i * WN + o] * ic + s_cb[o];
        agg[(size_t)i * WN + o] = 0.0f;
#pragma unroll
        for (int k = 0; k < WN; k++) acc += hv[k] * s_root[k * WN + o];
        h[(size_t)i * WN + o] = acc > 0.0f ? acc : 0.0f;
    }
}

__global__ void out_kernel(const float* __restrict__ h, const float* __restrict__ fc2_w,
                           const float* __restrict__ fc2_b, float* __restrict__ out, int n) {
    __shared__ float s_w[WN];
    __shared__ float s_b;
    int t = threadIdx.x;
    if (t < WN) s_w[t] = fc2_w[t];
    if (t == 0) s_b = fc2_b[0];
    __syncthreads();
    int i = blockIdx.x * blockDim.x + t;
    if (i >= n) return;
    float acc = s_b;
#pragma unroll
    for (int k = 0; k < WN; k++) acc += h[(size_t)i * WN + k] * s_w[k];
    out[i] = acc;
}

extern "C" void kernel_launch(void* const* d_in, const int* in_sizes, int n_in,
                              void* d_out, int out_size, void* d_ws, size_t ws_size,
                              hipStream_t stream) {
    const float* x      = (const float*)d_in[0];
    const int*   eidx   = (const int*)d_in[1];
    const float* ea     = (const float*)d_in[2];
    const float* fc1_w  = (const float*)d_in[3];
    const float* fc1_b  = (const float*)d_in[4];
    const float* fc2_w  = (const float*)d_in[5];
    const float* fc2_b  = (const float*)d_in[6];
    const float* kw1    = (const float*)d_in[7];
    const float* kb1    = (const float*)d_in[8];
    const float* kw2    = (const float*)d_in[9];
    const float* kb2    = (const float*)d_in[10];
    const float* root   = (const float*)d_in[11];
    const float* cbias  = (const float*)d_in[12];
    float* out = (float*)d_out;

    const int n = in_sizes[0] / 3;       // 50000
    const int e_cnt = in_sizes[2] / 3;   // 1600000

    // workspace layout (floats)
    float* ws  = (float*)d_ws;
    float* h   = ws;                         // n*WN
    float* agg = ws + (size_t)n * WN;        // n*WN
    float* inv = ws + (size_t)2 * n * WN;    // n
    int*   cnt = (int*)(ws + (size_t)2 * n * WN + n); // n

    const int B = 256;
    int grid_nw = (n * WN + B - 1) / B;
    int grid_n  = (n + B - 1) / B;
    int grid_e  = (e_cnt + B - 1) / B;

    zero_kernel<<<grid_nw, B, 0, stream>>>(agg, cnt, n, n * WN);
    h0_kernel<<<grid_n, B, 0, stream>>>(x, fc1_w, fc1_b, h, n);
    count_kernel<<<grid_e, B, 0, stream>>>(eidx, cnt, e_cnt);
    inv_kernel<<<grid_n, B, 0, stream>>>(cnt, inv, n);

    for (int d = 0; d < DEPTH; d++) {
        for (int c = 0; c < 3; c++) {
            edge_kernel<<<grid_e, B, 0, stream>>>(
                eidx, ea, h, agg,
                kw1 + (size_t)c * HID * 3, kb1 + (size_t)c * HID,
                kw2 + (size_t)c * WN * HID, kb2 + (size_t)c * WN, e_cnt);
            update_kernel<<<grid_n, B, 0, stream>>>(
                h, agg, inv, root + (size_t)c * WN * WN, cbias + (size_t)c * WN, n);
        }
    }
    out_kernel<<<grid_n, B, 0, stream>>>(h, fc2_w, fc2_b, out, n);
}

// Round 2
// 2109.736 us; speedup vs baseline: 14.9577x; 14.9577x over previous
//
#include <hip/hip_runtime.h>

#define WN 32          // WIDTH
#define HID 8          // WIDTH/4
#define DEPTH 4

__global__ void zero_kernel(int* __restrict__ cnt, int* __restrict__ cursor, int n) {
    int i = blockIdx.x * blockDim.x + threadIdx.x;
    if (i < n) { cnt[i] = 0; cursor[i] = 0; }
}

__global__ void count_kernel(const int* __restrict__ eidx, int* __restrict__ cnt, int e_cnt) {
    int e = blockIdx.x * blockDim.x + threadIdx.x;
    if (e >= e_cnt) return;
    atomicAdd(&cnt[eidx[e_cnt + e]], 1);
}

// Single-block exclusive scan over cnt -> row_ptr[n+1]; also inv = 1/max(cnt,1).
__global__ void scan_kernel(const int* __restrict__ cnt, int* __restrict__ row_ptr,
                            float* __restrict__ inv, int n) {
    __shared__ int s_wave[16];
    int t = threadIdx.x;
    int lane = t & 63;
    int wv = t >> 6;                 // 16 waves of 64
    int offset = 0;
    for (int base = 0; base < n; base += 1024) {
        int i = base + t;
        int v = (i < n) ? cnt[i] : 0;
        int x = v;
#pragma unroll
        for (int d = 1; d < 64; d <<= 1) {
            int y = __shfl_up(x, d, 64);
            if (lane >= d) x += y;
        }
        if (lane == 63) s_wave[wv] = x;
        __syncthreads();
        if (wv == 0 && lane < 16) {
            int y = s_wave[lane];
#pragma unroll
            for (int d = 1; d < 16; d <<= 1) {
                int z = __shfl_up(y, d, 64);
                if (lane >= d) y += z;
            }
            s_wave[lane] = y;        // inclusive over wave sums
        }
        __syncthreads();
        int waveoff = (wv > 0) ? s_wave[wv - 1] : 0;
        int total = s_wave[15];
        int incl = x + waveoff + offset;
        if (i < n) {
            row_ptr[i + 1] = incl;
            inv[i] = 1.0f / (float)(v > 1 ? v : 1);
        }
        offset += total;
        __syncthreads();             // protect s_wave before next chunk writes
    }
    if (t == 0) row_ptr[0] = 0;
}

// Permute edges into dst-CSR order: perm_src[pos], perm_ea[pos*3..]
__global__ void scatter_kernel(const int* __restrict__ eidx, const float* __restrict__ ea,
                               const int* __restrict__ row_ptr, int* __restrict__ cursor,
                               int* __restrict__ perm_src, float* __restrict__ perm_ea,
                               int e_cnt) {
    int e = blockIdx.x * blockDim.x + threadIdx.x;
    if (e >= e_cnt) return;
    int src = eidx[e];
    int dst = eidx[e_cnt + e];
    int pos = row_ptr[dst] + atomicAdd(&cursor[dst], 1);
    perm_src[pos] = src;
    perm_ea[3 * pos]     = ea[3 * e];
    perm_ea[3 * pos + 1] = ea[3 * e + 1];
    perm_ea[3 * pos + 2] = ea[3 * e + 2];
}

__global__ void h0_kernel(const float* __restrict__ x, const float* __restrict__ fc1_w,
                          const float* __restrict__ fc1_b, float* __restrict__ h, int n) {
    __shared__ float s_w[WN * 3];
    __shared__ float s_b[WN];
    int t = threadIdx.x;
    if (t < WN * 3) s_w[t] = fc1_w[t];
    if (t < WN) s_b[t] = fc1_b[t];
    __syncthreads();
    int i = blockIdx.x * blockDim.x + t;
    if (i >= n) return;
    float x0 = x[3 * i], x1 = x[3 * i + 1], x2 = x[3 * i + 2];
#pragma unroll
    for (int j = 0; j < WN; j++) {
        h[(size_t)i * WN + j] = s_b[j] + s_w[j * 3] * x0 + s_w[j * 3 + 1] * x1 + s_w[j * 3 + 2] * x2;
    }
}

// One thread per (node, channel). Accumulate in-edges (no atomics), recompute
// edge-MLP weight in-register, fused epilogue: mean + h@root + bias + relu.
__global__ void gather_kernel(const int* __restrict__ row_ptr, const int* __restrict__ perm_src,
                              const float* __restrict__ perm_ea,
                              const float* __restrict__ h_in, float* __restrict__ h_out,
                              const float* __restrict__ inv,
                              const float* __restrict__ kw1, const float* __restrict__ kb1,
                              const float* __restrict__ kw2, const float* __restrict__ kb2,
                              const float* __restrict__ root, const float* __restrict__ cbias,
                              int n) {
    __shared__ float s_kw1[HID * 3];
    __shared__ float s_kb1[HID];
    __shared__ float s_kw2[WN * HID];
    __shared__ float s_kb2[WN];
    __shared__ float s_cb[WN];
    __shared__ float s_root[WN * WN];
    __shared__ float s_h[8][WN];     // 256 threads = 8 nodes x 32 channels
    int t = threadIdx.x;
    for (int i = t; i < WN * WN; i += 256) s_root[i] = root[i];
    if (t < HID * 3) s_kw1[t] = kw1[t];
    if (t < HID) s_kb1[t] = kb1[t];
    if (t < WN * HID) s_kw2[t] = kw2[t];   // 256 exactly
    if (t < WN) { s_kb2[t] = kb2[t]; s_cb[t] = cbias[t]; }
    __syncthreads();

    int grp = t >> 5;
    int ch = t & 31;
    int node = blockIdx.x * 8 + grp;

    float hval = (node < n) ? h_in[(size_t)node * WN + ch] : 0.0f;
    s_h[grp][ch] = hval;
    __syncthreads();
    if (node >= n) return;

    float w2[HID];
#pragma unroll
    for (int j = 0; j < HID; j++) w2[j] = s_kw2[ch * HID + j];
    float b2 = s_kb2[ch];

    float acc = 0.0f;
    int e0 = row_ptr[node], e1 = row_ptr[node + 1];
    for (int e = e0; e < e1; e++) {
        int src = perm_src[e];
        float a0 = perm_ea[3 * e], a1 = perm_ea[3 * e + 1], a2 = perm_ea[3 * e + 2];
        float w = b2;
#pragma unroll
        for (int j = 0; j < HID; j++) {
            float v = s_kb1[j] + s_kw1[j * 3] * a0 + s_kw1[j * 3 + 1] * a1 + s_kw1[j * 3 + 2] * a2;
            v = v > 0.0f ? v : 0.0f;
            w += w2[j] * v;
        }
        acc += h_in[(size_t)src * WN + ch] * w;
    }

    float r = acc * inv[node] + s_cb[ch];
    const float* srow = s_h[grp];
#pragma unroll
    for (int k = 0; k < WN; k++) r += srow[k] * s_root[k * WN + ch];
    h_out[(size_t)node * WN + ch] = r > 0.0f ? r : 0.0f;
}

__global__ void out_kernel(const float* __restrict__ h, const float* __restrict__ fc2_w,
                           const float* __restrict__ fc2_b, float* __restrict__ out, int n) {
    __shared__ float s_w[WN];
    __shared__ float s_b;
    int t = threadIdx.x;
    if (t < WN) s_w[t] = fc2_w[t];
    if (t == 0) s_b = fc2_b[0];
    __syncthreads();
    int i = blockIdx.x * blockDim.x + t;
    if (i >= n) return;
    float acc = s_b;
#pragma unroll
    for (int k = 0; k < WN; k++) acc += h[(size_t)i * WN + k] * s_w[k];
    out[i] = acc;
}

extern "C" void kernel_launch(void* const* d_in, const int* in_sizes, int n_in,
                              void* d_out, int out_size, void* d_ws, size_t ws_size,
                              hipStream_t stream) {
    const float* x      = (const float*)d_in[0];
    const int*   eidx   = (const int*)d_in[1];
    const float* ea     = (const float*)d_in[2];
    const float* fc1_w  = (const float*)d_in[3];
    const float* fc1_b  = (const float*)d_in[4];
    const float* fc2_w  = (const float*)d_in[5];
    const float* fc2_b  = (const float*)d_in[6];
    const float* kw1    = (const float*)d_in[7];
    const float* kb1    = (const float*)d_in[8];
    const float* kw2    = (const float*)d_in[9];
    const float* kb2    = (const float*)d_in[10];
    const float* root   = (const float*)d_in[11];
    const float* cbias  = (const float*)d_in[12];
    float* out = (float*)d_out;

    const int n = in_sizes[0] / 3;       // 50000
    const int e_cnt = in_sizes[2] / 3;   // 1600000

    // workspace layout (4-byte units)
    float* ws = (float*)d_ws;
    size_t off = 0;
    float* hA       = ws + off; off += (size_t)n * WN;
    float* hB       = ws + off; off += (size_t)n * WN;
    float* inv      = ws + off; off += n;
    int*   cnt      = (int*)(ws + off); off += n;
    int*   cursor   = (int*)(ws + off); off += n;
    int*   row_ptr  = (int*)(ws + off); off += (n + 1);
    int*   perm_src = (int*)(ws + off); off += e_cnt;
    float* perm_ea  = ws + off; off += (size_t)3 * e_cnt;

    const int B = 256;
    int grid_n  = (n + B - 1) / B;
    int grid_e  = (e_cnt + B - 1) / B;
    int grid_g  = (n + 7) / 8;

    zero_kernel<<<grid_n, B, 0, stream>>>(cnt, cursor, n);
    count_kernel<<<grid_e, B, 0, stream>>>(eidx, cnt, e_cnt);
    scan_kernel<<<1, 1024, 0, stream>>>(cnt, row_ptr, inv, n);
    scatter_kernel<<<grid_e, B, 0, stream>>>(eidx, ea, row_ptr, cursor, perm_src, perm_ea, e_cnt);
    h0_kernel<<<grid_n, B, 0, stream>>>(x, fc1_w, fc1_b, hA, n);

    float* hin = hA;
    float* hout = hB;
    for (int d = 0; d < DEPTH; d++) {
        for (int c = 0; c < 3; c++) {
            gather_kernel<<<grid_g, B, 0, stream>>>(
                row_ptr, perm_src, perm_ea, hin, hout, inv,
                kw1 + (size_t)c * HID * 3, kb1 + (size_t)c * HID,
                kw2 + (size_t)c * WN * HID, kb2 + (size_t)c * WN,
                root + (size_t)c * WN * WN, cbias + (size_t)c * WN, n);
            float* tmp = hin; hin = hout; hout = tmp;
        }
    }
    // 12 swaps -> final h is in hin
    out_kernel<<<grid_n, B, 0, stream>>>(hin, fc2_w, fc2_b, out, n);
}

// Round 3
// 1234.362 us; speedup vs baseline: 25.5654x; 1.7092x over previous
//
#include <hip/hip_runtime.h>

#define WN 32          // WIDTH
#define HID 8          // WIDTH/4
#define DEPTH 4

__global__ void zero_kernel(int* __restrict__ cnt, int* __restrict__ cursor, int n) {
    int i = blockIdx.x * blockDim.x + threadIdx.x;
    if (i < n) { cnt[i] = 0; cursor[i] = 0; }
}

__global__ void count_kernel(const int* __restrict__ eidx, int* __restrict__ cnt, int e_cnt) {
    int e = blockIdx.x * blockDim.x + threadIdx.x;
    if (e >= e_cnt) return;
    atomicAdd(&cnt[eidx[e_cnt + e]], 1);
}

// Single-block exclusive scan over cnt -> row_ptr[n+1]; also inv = 1/max(cnt,1).
__global__ void scan_kernel(const int* __restrict__ cnt, int* __restrict__ row_ptr,
                            float* __restrict__ inv, int n) {
    __shared__ int s_wave[16];
    int t = threadIdx.x;
    int lane = t & 63;
    int wv = t >> 6;                 // 16 waves of 64
    int offset = 0;
    for (int base = 0; base < n; base += 1024) {
        int i = base + t;
        int v = (i < n) ? cnt[i] : 0;
        int x = v;
#pragma unroll
        for (int d = 1; d < 64; d <<= 1) {
            int y = __shfl_up(x, d, 64);
            if (lane >= d) x += y;
        }
        if (lane == 63) s_wave[wv] = x;
        __syncthreads();
        if (wv == 0 && lane < 16) {
            int y = s_wave[lane];
#pragma unroll
            for (int d = 1; d < 16; d <<= 1) {
                int z = __shfl_up(y, d, 64);
                if (lane >= d) y += z;
            }
            s_wave[lane] = y;        // inclusive over wave sums
        }
        __syncthreads();
        int waveoff = (wv > 0) ? s_wave[wv - 1] : 0;
        int total = s_wave[15];
        int incl = x + waveoff + offset;
        if (i < n) {
            row_ptr[i + 1] = incl;
            inv[i] = 1.0f / (float)(v > 1 ? v : 1);
        }
        offset += total;
        __syncthreads();
    }
    if (t == 0) row_ptr[0] = 0;
}

// Permute edges into dst-CSR order: perm_src[pos], perm_ea[pos*3..]
__global__ void scatter_kernel(const int* __restrict__ eidx, const float* __restrict__ ea,
                               const int* __restrict__ row_ptr, int* __restrict__ cursor,
                               int* __restrict__ perm_src, float* __restrict__ perm_ea,
                               int e_cnt) {
    int e = blockIdx.x * blockDim.x + threadIdx.x;
    if (e >= e_cnt) return;
    int src = eidx[e];
    int dst = eidx[e_cnt + e];
    int pos = row_ptr[dst] + atomicAdd(&cursor[dst], 1);
    perm_src[pos] = src;
    perm_ea[3 * pos]     = ea[3 * e];
    perm_ea[3 * pos + 1] = ea[3 * e + 1];
    perm_ea[3 * pos + 2] = ea[3 * e + 2];
}

// Precompute hid[e][8] = relu(kw1_c @ ea_e + kb1_c) for all 3 channel-blocks.
// Layer-invariant: computed once per call, reused by all 12 gather dispatches.
__global__ void hid_kernel(const float* __restrict__ perm_ea,
                           const float* __restrict__ kw1, const float* __restrict__ kb1,
                           float* __restrict__ hid_buf, int e_cnt) {
    int e = blockIdx.x * blockDim.x + threadIdx.x;
    int c = blockIdx.y;
    if (e >= e_cnt) return;
    const float* w1 = kw1 + (size_t)c * HID * 3;   // uniform -> scalar loads
    const float* b1 = kb1 + (size_t)c * HID;
    float a0 = perm_ea[3 * e], a1 = perm_ea[3 * e + 1], a2 = perm_ea[3 * e + 2];
    float4 lo, hi;
    float v[HID];
#pragma unroll
    for (int j = 0; j < HID; j++) {
        float u = b1[j] + w1[j * 3] * a0 + w1[j * 3 + 1] * a1 + w1[j * 3 + 2] * a2;
        v[j] = u > 0.0f ? u : 0.0f;
    }
    lo.x = v[0]; lo.y = v[1]; lo.z = v[2]; lo.w = v[3];
    hi.x = v[4]; hi.y = v[5]; hi.z = v[6]; hi.w = v[7];
    float4* dst4 = (float4*)(hid_buf + ((size_t)c * e_cnt + e) * HID);
    dst4[0] = lo;
    dst4[1] = hi;
}

__global__ void h0_kernel(const float* __restrict__ x, const float* __restrict__ fc1_w,
                          const float* __restrict__ fc1_b, float* __restrict__ h, int n) {
    __shared__ float s_w[WN * 3];
    __shared__ float s_b[WN];
    int t = threadIdx.x;
    if (t < WN * 3) s_w[t] = fc1_w[t];
    if (t < WN) s_b[t] = fc1_b[t];
    __syncthreads();
    int i = blockIdx.x * blockDim.x + t;
    if (i >= n) return;
    float x0 = x[3 * i], x1 = x[3 * i + 1], x2 = x[3 * i + 2];
#pragma unroll
    for (int j = 0; j < WN; j++) {
        h[(size_t)i * WN + j] = s_b[j] + s_w[j * 3] * x0 + s_w[j * 3 + 1] * x1 + s_w[j * 3 + 2] * x2;
    }
}

// Fast path: hid precomputed. One thread per (node, channel).
// Per edge: 1 src load + 2 float4 hid loads (wave-broadcast) + 8 FMA (w) +
// 1 coalesced h-gather + 1 FMA. Fused epilogue: mean + h@root + bias + relu.
__global__ void gather_hid_kernel(const int* __restrict__ row_ptr, const int* __restrict__ perm_src,
                                  const float* __restrict__ hid_c,
                                  const float* __restrict__ h_in, float* __restrict__ h_out,
                                  const float* __restrict__ inv,
                                  const float* __restrict__ kw2, const float* __restrict__ kb2,
                                  const float* __restrict__ root, const float* __restrict__ cbias,
                                  int n) {
    __shared__ float s_root[WN * WN];
    __shared__ float s_h[8][WN];
    int t = threadIdx.x;
    for (int i = t; i < WN * WN; i += 256) s_root[i] = root[i];

    int grp = t >> 5;
    int ch = t & 31;
    int node = blockIdx.x * 8 + grp;
    bool valid = node < n;

    // per-thread weight column (L1-cached vector loads)
    const float4* kw2v = (const float4*)(kw2 + ch * HID);
    float4 w2lo = kw2v[0], w2hi = kw2v[1];
    float b2 = kb2[ch];
    float cb = cbias[ch];

    float hval = valid ? h_in[(size_t)node * WN + ch] : 0.0f;
    s_h[grp][ch] = hval;
    __syncthreads();

    float acc = 0.0f;
    if (valid) {
        int e0 = row_ptr[node], e1 = row_ptr[node + 1];
        const float4* hid4 = (const float4*)hid_c;
#pragma unroll 4
        for (int e = e0; e < e1; e++) {
            int src = perm_src[e];
            float4 u = hid4[2 * (size_t)e];
            float4 v = hid4[2 * (size_t)e + 1];
            float w = b2 + w2lo.x * u.x + w2lo.y * u.y + w2lo.z * u.z + w2lo.w * u.w
                         + w2hi.x * v.x + w2hi.y * v.y + w2hi.z * v.z + w2hi.w * v.w;
            acc += h_in[(size_t)src * WN + ch] * w;
        }
    }
    if (!valid) return;

    float r = acc * inv[node] + cb;
    const float* srow = s_h[grp];
#pragma unroll
    for (int k = 0; k < WN; k++) r += srow[k] * s_root[k * WN + ch];
    h_out[(size_t)node * WN + ch] = r > 0.0f ? r : 0.0f;
}

// Fallback (small ws): inline hid recompute — R1-proven kernel.
__global__ void gather_kernel(const int* __restrict__ row_ptr, const int* __restrict__ perm_src,
                              const float* __restrict__ perm_ea,
                              const float* __restrict__ h_in, float* __restrict__ h_out,
                              const float* __restrict__ inv,
                              const float* __restrict__ kw1, const float* __restrict__ kb1,
                              const float* __restrict__ kw2, const float* __restrict__ kb2,
                              const float* __restrict__ root, const float* __restrict__ cbias,
                              int n) {
    __shared__ float s_kw1[HID * 3];
    __shared__ float s_kb1[HID];
    __shared__ float s_kw2[WN * HID];
    __shared__ float s_kb2[WN];
    __shared__ float s_cb[WN];
    __shared__ float s_root[WN * WN];
    __shared__ float s_h[8][WN];
    int t = threadIdx.x;
    for (int i = t; i < WN * WN; i += 256) s_root[i] = root[i];
    if (t < HID * 3) s_kw1[t] = kw1[t];
    if (t < HID) s_kb1[t] = kb1[t];
    if (t < WN * HID) s_kw2[t] = kw2[t];
    if (t < WN) { s_kb2[t] = kb2[t]; s_cb[t] = cbias[t]; }
    __syncthreads();

    int grp = t >> 5;
    int ch = t & 31;
    int node = blockIdx.x * 8 + grp;

    float hval = (node < n) ? h_in[(size_t)node * WN + ch] : 0.0f;
    s_h[grp][ch] = hval;
    __syncthreads();
    if (node >= n) return;

    float w2[HID];
#pragma unroll
    for (int j = 0; j < HID; j++) w2[j] = s_kw2[ch * HID + j];
    float b2 = s_kb2[ch];

    float acc = 0.0f;
    int e0 = row_ptr[node], e1 = row_ptr[node + 1];
    for (int e = e0; e < e1; e++) {
        int src = perm_src[e];
        float a0 = perm_ea[3 * e], a1 = perm_ea[3 * e + 1], a2 = perm_ea[3 * e + 2];
        float w = b2;
#pragma unroll
        for (int j = 0; j < HID; j++) {
            float v = s_kb1[j] + s_kw1[j * 3] * a0 + s_kw1[j * 3 + 1] * a1 + s_kw1[j * 3 + 2] * a2;
            v = v > 0.0f ? v : 0.0f;
            w += w2[j] * v;
        }
        acc += h_in[(size_t)src * WN + ch] * w;
    }

    float r = acc * inv[node] + s_cb[ch];
    const float* srow = s_h[grp];
#pragma unroll
    for (int k = 0; k < WN; k++) r += srow[k] * s_root[k * WN + ch];
    h_out[(size_t)node * WN + ch] = r > 0.0f ? r : 0.0f;
}

__global__ void out_kernel(const float* __restrict__ h, const float* __restrict__ fc2_w,
                           const float* __restrict__ fc2_b, float* __restrict__ out, int n) {
    __shared__ float s_w[WN];
    __shared__ float s_b;
    int t = threadIdx.x;
    if (t < WN) s_w[t] = fc2_w[t];
    if (t == 0) s_b = fc2_b[0];
    __syncthreads();
    int i = blockIdx.x * blockDim.x + t;
    if (i >= n) return;
    float acc = s_b;
#pragma unroll
    for (int k = 0; k < WN; k++) acc += h[(size_t)i * WN + k] * s_w[k];
    out[i] = acc;
}

extern "C" void kernel_launch(void* const* d_in, const int* in_sizes, int n_in,
                              void* d_out, int out_size, void* d_ws, size_t ws_size,
                              hipStream_t stream) {
    const float* x      = (const float*)d_in[0];
    const int*   eidx   = (const int*)d_in[1];
    const float* ea     = (const float*)d_in[2];
    const float* fc1_w  = (const float*)d_in[3];
    const float* fc1_b  = (const float*)d_in[4];
    const float* fc2_w  = (const float*)d_in[5];
    const float* fc2_b  = (const float*)d_in[6];
    const float* kw1    = (const float*)d_in[7];
    const float* kb1    = (const float*)d_in[8];
    const float* kw2    = (const float*)d_in[9];
    const float* kb2    = (const float*)d_in[10];
    const float* root   = (const float*)d_in[11];
    const float* cbias  = (const float*)d_in[12];
    float* out = (float*)d_out;

    const int n = in_sizes[0] / 3;       // 50000
    const int e_cnt = in_sizes[2] / 3;   // 1600000

    // workspace layout (floats, 16B-aligned sections)
    auto pad4 = [](size_t v) { return (v + 3) & ~(size_t)3; };
    float* ws = (float*)d_ws;
    size_t off = 0;
    float* hA       = ws + off; off += pad4((size_t)n * WN);
    float* hB       = ws + off; off += pad4((size_t)n * WN);
    float* inv      = ws + off; off += pad4(n);
    int*   cnt      = (int*)(ws + off); off += pad4(n);
    int*   cursor   = (int*)(ws + off); off += pad4(n);
    int*   row_ptr  = (int*)(ws + off); off += pad4(n + 1);
    int*   perm_src = (int*)(ws + off); off += pad4(e_cnt);
    float* perm_ea  = ws + off; off += pad4((size_t)3 * e_cnt);
    float* hid_buf  = ws + off; off += (size_t)3 * e_cnt * HID;
    bool full_path = (ws_size >= off * sizeof(float));

    const int B = 256;
    int grid_n  = (n + B - 1) / B;
    int grid_e  = (e_cnt + B - 1) / B;
    int grid_g  = (n + 7) / 8;

    zero_kernel<<<grid_n, B, 0, stream>>>(cnt, cursor, n);
    count_kernel<<<grid_e, B, 0, stream>>>(eidx, cnt, e_cnt);
    scan_kernel<<<1, 1024, 0, stream>>>(cnt, row_ptr, inv, n);
    scatter_kernel<<<grid_e, B, 0, stream>>>(eidx, ea, row_ptr, cursor, perm_src, perm_ea, e_cnt);
    if (full_path) {
        hid_kernel<<<dim3(grid_e, 3), B, 0, stream>>>(perm_ea, kw1, kb1, hid_buf, e_cnt);
    }
    h0_kernel<<<grid_n, B, 0, stream>>>(x, fc1_w, fc1_b, hA, n);

    float* hin = hA;
    float* hout = hB;
    for (int d = 0; d < DEPTH; d++) {
        for (int c = 0; c < 3; c++) {
            if (full_path) {
                gather_hid_kernel<<<grid_g, B, 0, stream>>>(
                    row_ptr, perm_src, hid_buf + (size_t)c * e_cnt * HID,
                    hin, hout, inv,
                    kw2 + (size_t)c * WN * HID, kb2 + (size_t)c * WN,
                    root + (size_t)c * WN * WN, cbias + (size_t)c * WN, n);
            } else {
                gather_kernel<<<grid_g, B, 0, stream>>>(
                    row_ptr, perm_src, perm_ea, hin, hout, inv,
                    kw1 + (size_t)c * HID * 3, kb1 + (size_t)c * HID,
                    kw2 + (size_t)c * WN * HID, kb2 + (size_t)c * WN,
                    root + (size_t)c * WN * WN, cbias + (size_t)c * WN, n);
            }
            float* tmp = hin; hin = hout; hout = tmp;
        }
    }
    // 12 swaps -> final h is in hin
    out_kernel<<<grid_n, B, 0, stream>>>(hin, fc2_w, fc2_b, out, n);
}